// Round 10
// baseline (115.039 us; speedup 1.0000x reference)
//
#include <hip/hip_runtime.h>

// Implicit-GEMM conv2d via bf16 MFMA (32x32x16), ws pre-pack.
// R10 = R6 (best, 99us) + write-path fix:
//   (1) natural block order (concurrent blocks write adjacent n -> DRAM row hits)
//   (2) LDS-transpose epilogue: C tile -> LDS -> float4/lane linear stores
//       (512B contiguous per co-row chunk per instruction, 16B aligned).
// GEMM: M=256=Cout, N=123008, K=1152 (k = tap*128+ci).
// Tile 128x128xBK64, 256 thr / 4 waves (2Mx2N), wave tile 64x64 = 2x2 of
// 32x32x16. LDS 2 x 32KB double-buffer -> 2 blocks/CU.
//   A' [256][1152] bf16   (from w [256][128][3][3] f32)
//   xp [32][64][64][128] bf16 (NHWC, from x [32][128][64][64] f32)

using bf16x8 = __attribute__((ext_vector_type(8))) __bf16;
using f32x4  = __attribute__((ext_vector_type(4))) float;
using f32x16 = __attribute__((ext_vector_type(16))) float;

constexpr int CIN  = 128;
constexpr int HW   = 64;
constexpr int COUT = 256;
constexpr int OW   = 62;
constexpr int NS   = 62 * 62;          // 3844 (multiple of 4)
constexpr int NTOT = 32 * NS;          // 123008
constexpr int KTOT = 9 * CIN;          // 1152
constexpr int BM = 128, BN = 128, BK = 64;
constexpr int NT = KTOT / BK;          // 18 K-tiles
constexpr int NWG = 2 * (NTOT / BN);   // 1922

constexpr size_t AP_BYTES = (size_t)COUT * KTOT * 2;            // 589824
constexpr size_t XP_BYTES = (size_t)32 * HW * HW * CIN * 2;     // 33554432
constexpr size_t WS_NEEDED = AP_BYTES + XP_BYTES;

constexpr int BUF  = 32768;            // per K-tile buffer: A 16KB + B 16KB
constexpr int BOFF = 16384;            // B offset inside buffer

__device__ __forceinline__ unsigned short f2bf(float f) {
  unsigned u = __float_as_uint(f);
  u += 0x7fffu + ((u >> 16) & 1u);     // RNE
  return (unsigned short)(u >> 16);
}
__device__ __forceinline__ unsigned pack2(float a, float b) {
  return (unsigned)f2bf(a) | ((unsigned)f2bf(b) << 16);
}

__device__ __forceinline__ void gld16(const void* g, void* l) {
  __builtin_amdgcn_global_load_lds(
      (const __attribute__((address_space(1))) unsigned int*)g,
      (__attribute__((address_space(3))) unsigned int*)l, 16, 0, 0);
}

// ---------------- prepack kernels ----------------

__global__ __launch_bounds__(256)
void prepack_w(const float* __restrict__ w, unsigned* __restrict__ ap32) {
  const int idx = blockIdx.x * 256 + threadIdx.x;     // 0..147455
  const int co  = idx / 576;
  const int k2  = idx - co * 576;
  const int k   = k2 * 2;
  const int tap = k >> 7;
  const int ci  = k & 127;
  const float v0 = w[(co * 128 + ci) * 9 + tap];
  const float v1 = w[(co * 128 + ci + 1) * 9 + tap];
  ap32[idx] = pack2(v0, v1);
}

__global__ __launch_bounds__(256)
void prepack_x(const float* __restrict__ x, unsigned* __restrict__ xp32) {
  const int bh = blockIdx.x;           // b*64 + h
  const int b  = bh >> 6, h = bh & 63;
  const int t  = threadIdx.x;
  const int c  = t & 63;               // ci-pair index (ci = 2c, 2c+1)
  const int w0 = (t >> 6) * 16;

  const float* p0 = x + (((size_t)(b * 128 + 2 * c) * HW) + h) * HW + w0;
  const float* p1 = p0 + (size_t)HW * HW;
  float r0[16], r1[16];
#pragma unroll
  for (int j = 0; j < 4; ++j) {
    *reinterpret_cast<float4*>(&r0[j * 4]) = reinterpret_cast<const float4*>(p0)[j];
    *reinterpret_cast<float4*>(&r1[j * 4]) = reinterpret_cast<const float4*>(p1)[j];
  }
  unsigned* o = xp32 + ((size_t)bh * HW + w0) * 64 + c;
#pragma unroll
  for (int j = 0; j < 16; ++j)
    o[j * 64] = pack2(r0[j], r1[j]);
}

// ---------------- main kernel ----------------

__global__ __launch_bounds__(256, 2)
void conv_main(const unsigned short* __restrict__ Ap,
               const unsigned short* __restrict__ Xp,
               float* __restrict__ out) {
  __shared__ __align__(16) char lds[2 * BUF];   // 64 KiB -> 2 blocks/CU

  const int tid  = threadIdx.x;
  const int lane = tid & 63;
  const int wid  = tid >> 6;       // 0..3
  const int wm   = wid >> 1;
  const int wn   = wid & 1;

  // natural order: co-half innermost, adjacent f = same/adjacent n panels
  const int f = blockIdx.x;
  const int co_base = (f & 1) * BM;
  const int n_base  = (f >> 1) * BN;

  const int l3  = lane >> 3;
  const int sw8 = ((lane & 7) ^ l3) * 8;
  int aoff[4];
  unsigned xoff[4];
#pragma unroll
  for (int q = 0; q < 4; ++q) {
    const int rr = wid * 32 + q * 8 + l3;
    aoff[q] = (co_base + rr) * KTOT + sw8;
    const unsigned n  = n_base + rr;
    const unsigned bi = n / NS;
    const unsigned s0 = n - bi * NS;
    const unsigned oh = s0 / OW;
    const unsigned ww = s0 - oh * OW;
    xoff[q] = ((bi * HW + oh) * HW + ww) * CIN + sw8;
  }

  const int cl = lane & 31;
  const int gl = lane >> 5;
  int sA[4];
#pragma unroll
  for (int kf = 0; kf < 4; ++kf)
    sA[kf] = ((kf * 2 + gl) ^ (lane & 7)) * 16;
  const int abase = (wm * 64 + cl) * 128;
  const int bbase = BOFF + (wn * 64 + cl) * 128;

  f32x16 acc[2][2] = {};

  auto STAGE = [&](int t, char* dst) {
    const int tap = t >> 1;
    const int kh  = tap / 3;
    const int kw  = tap - kh * 3;
    const int ak  = tap * CIN + (t & 1) * 64;
    const int xk  = (kh * HW + kw) * CIN + (t & 1) * 64;
#pragma unroll
    for (int q = 0; q < 4; ++q)
      gld16(Ap + aoff[q] + ak, dst + (wid * 32 + q * 8) * 128);
#pragma unroll
    for (int q = 0; q < 4; ++q)
      gld16(Xp + xoff[q] + xk, dst + BOFF + (wid * 32 + q * 8) * 128);
  };

  STAGE(0, lds);

#pragma unroll
  for (int t = 0; t < NT; ++t) {
    const char* cur = lds + (t & 1) * BUF;
    asm volatile("s_waitcnt vmcnt(0)" ::: "memory");
    __builtin_amdgcn_s_barrier();
    if (t + 1 < NT) STAGE(t + 1, lds + ((t + 1) & 1) * BUF);

    bf16x8 a[2][4], b[2][4];
#pragma unroll
    for (int mt = 0; mt < 2; ++mt)
#pragma unroll
      for (int kf = 0; kf < 4; ++kf)
        a[mt][kf] = *reinterpret_cast<const bf16x8*>(cur + abase + mt * 4096 + sA[kf]);
#pragma unroll
    for (int nt = 0; nt < 2; ++nt)
#pragma unroll
      for (int kf = 0; kf < 4; ++kf)
        b[nt][kf] = *reinterpret_cast<const bf16x8*>(cur + bbase + nt * 4096 + sA[kf]);

#pragma unroll
    for (int kf = 0; kf < 4; ++kf)
#pragma unroll
      for (int mt = 0; mt < 2; ++mt)
#pragma unroll
        for (int nt = 0; nt < 2; ++nt)
          acc[mt][nt] = __builtin_amdgcn_mfma_f32_32x32x16_bf16(
              a[mt][kf], b[nt][kf], acc[mt][nt], 0, 0, 0);
  }

  // ---- epilogue: C tile -> LDS [128co][128n] f32 -> float4/lane stores ----
  // 32x32 C/D layout: col(n) = cl, row(co) = (r&3)+8*(r>>2)+4*gl.
  float* lf = reinterpret_cast<float*>(lds);
  // all waves' last-iter ds_reads are consumed (MFMA data-dep) before they
  // reach this barrier; after it, LDS is reusable.
  asm volatile("s_waitcnt vmcnt(0) lgkmcnt(0)" ::: "memory");
  __builtin_amdgcn_s_barrier();

#pragma unroll
  for (int mt = 0; mt < 2; ++mt)
#pragma unroll
    for (int nt = 0; nt < 2; ++nt) {
      const int nn = wn * 64 + nt * 32 + cl;
#pragma unroll
      for (int r = 0; r < 16; ++r) {
        const int co = wm * 64 + mt * 32 + gl * 4 + (r & 3) + 8 * (r >> 2);
        lf[co * 128 + nn] = acc[mt][nt][r];
      }
    }
  asm volatile("s_waitcnt lgkmcnt(0)" ::: "memory");
  __builtin_amdgcn_s_barrier();

  // 16 passes x (ds_read_b128 + global_store_dwordx4); addresses ascend.
  // n4 and NS are multiples of 4 -> a float4 never crosses a batch boundary
  // and all stores are 16B-aligned.
#pragma unroll
  for (int p = 0; p < 16; ++p) {
    const int e  = p * 1024 + tid * 4;     // element in [128co][128n]
    const int co = e >> 7;
    const int n4 = e & 127;
    const float4 v = *reinterpret_cast<const float4*>(&lf[e]);
    const unsigned n  = n_base + n4;
    const unsigned b2 = n / NS;
    const unsigned s2 = n - b2 * NS;
    *reinterpret_cast<float4*>(
        out + (size_t)b2 * (COUT * NS) + (size_t)(co_base + co) * NS + s2) = v;
  }
}

// ---------------- fallback (no-ws path, round-1 proven) ----------------

__global__ __launch_bounds__(256)
void conv_fallback(const float* __restrict__ x, const float* __restrict__ w,
                   float* __restrict__ out) {
  __shared__ __align__(16) unsigned short As[128 * 32];
  __shared__ __align__(16) unsigned short Bs[128 * 32];

  const int t    = threadIdx.x;
  const int lane = t & 63;
  const int wid  = t >> 6;
  const int wm   = wid >> 1;
  const int wn   = wid & 1;
  const int co_base = blockIdx.x * 128;
  const int n_base  = blockIdx.y * 128;

  const int bn  = t & 127;
  const int bg0 = t >> 7;
  const unsigned n0   = n_base + bn;
  const unsigned bidx = n0 / NS;
  const unsigned s0   = n0 - bidx * NS;
  const unsigned oh   = s0 / OW;
  const unsigned ow   = s0 - oh * OW;
  const float* xb = x + (bidx * (CIN * HW * HW) + oh * HW + ow);

  const int am  = t & 127;
  const int ag0 = (t >> 7) * 2;
  const float* wb = w + (co_base + am) * KTOT;

  f32x4 acc[4][4] = {};

  for (int ks = 0; ks < 36; ++ks) {
    const int tap = ks >> 2;
    const int ci0 = (ks & 3) * 32;
    const int kh  = tap / 3;
    const int kw  = tap - kh * 3;
    const int xo  = kh * HW + kw;

    float av[2][8], bv[2][8];
#pragma unroll
    for (int gi = 0; gi < 2; ++gi) {
      const int g = ag0 + gi;
#pragma unroll
      for (int j = 0; j < 8; ++j)
        av[gi][j] = wb[(ci0 + g * 8 + j) * 9 + tap];
    }
#pragma unroll
    for (int gi = 0; gi < 2; ++gi) {
      const int g = bg0 + gi * 2;
#pragma unroll
      for (int j = 0; j < 8; ++j)
        bv[gi][j] = xb[xo + (ci0 + g * 8 + j) * (HW * HW)];
    }

    __syncthreads();

#pragma unroll
    for (int gi = 0; gi < 2; ++gi) {
      const int g = ag0 + gi;
      uint4 pv;
      pv.x = pack2(av[gi][0], av[gi][1]);
      pv.y = pack2(av[gi][2], av[gi][3]);
      pv.z = pack2(av[gi][4], av[gi][5]);
      pv.w = pack2(av[gi][6], av[gi][7]);
      *reinterpret_cast<uint4*>(&As[am * 32 + ((g ^ ((am >> 1) & 3)) << 3)]) = pv;
    }
#pragma unroll
    for (int gi = 0; gi < 2; ++gi) {
      const int g = bg0 + gi * 2;
      uint4 pv;
      pv.x = pack2(bv[gi][0], bv[gi][1]);
      pv.y = pack2(bv[gi][2], bv[gi][3]);
      pv.z = pack2(bv[gi][4], bv[gi][5]);
      pv.w = pack2(bv[gi][6], bv[gi][7]);
      *reinterpret_cast<uint4*>(&Bs[bn * 32 + ((g ^ ((bn >> 1) & 3)) << 3)]) = pv;
    }

    __syncthreads();

    bf16x8 af[4], bfr[4];
    const int g = lane >> 4;
#pragma unroll
    for (int mi = 0; mi < 4; ++mi) {
      const int m = wm * 64 + mi * 16 + (lane & 15);
      af[mi] = *reinterpret_cast<const bf16x8*>(&As[m * 32 + ((g ^ ((m >> 1) & 3)) << 3)]);
    }
#pragma unroll
    for (int ni = 0; ni < 4; ++ni) {
      const int nn = wn * 64 + ni * 16 + (lane & 15);
      bfr[ni] = *reinterpret_cast<const bf16x8*>(&Bs[nn * 32 + ((g ^ ((nn >> 1) & 3)) << 3)]);
    }
#pragma unroll
    for (int mi = 0; mi < 4; ++mi)
#pragma unroll
      for (int ni = 0; ni < 4; ++ni)
        acc[mi][ni] = __builtin_amdgcn_mfma_f32_16x16x32_bf16(af[mi], bfr[ni],
                                                              acc[mi][ni], 0, 0, 0);
  }

#pragma unroll
  for (int ni = 0; ni < 4; ++ni) {
    const unsigned n  = n_base + wn * 64 + ni * 16 + (lane & 15);
    const unsigned b2 = n / NS;
    const unsigned s2 = n - b2 * NS;
    float* op = out + (size_t)b2 * (COUT * NS) + s2
                    + (size_t)(co_base + wm * 64 + (lane >> 4) * 4) * NS;
#pragma unroll
    for (int mi = 0; mi < 4; ++mi)
#pragma unroll
      for (int r = 0; r < 4; ++r)
        op[(mi * 16 + r) * NS] = acc[mi][ni][r];
  }
}

extern "C" void kernel_launch(void* const* d_in, const int* in_sizes, int n_in,
                              void* d_out, int out_size, void* d_ws, size_t ws_size,
                              hipStream_t stream) {
  const float* x = (const float*)d_in[0];   // [32,128,64,64]
  const float* w = (const float*)d_in[1];   // [256,128,3,3]
  float* out = (float*)d_out;               // [32,256,62,62]

  if (ws_size >= WS_NEEDED) {
    unsigned* ap32 = (unsigned*)d_ws;
    unsigned short* Ap = (unsigned short*)d_ws;
    unsigned short* Xp = (unsigned short*)((char*)d_ws + AP_BYTES);
    unsigned* xp32 = (unsigned*)Xp;
    prepack_w<<<576, 256, 0, stream>>>(w, ap32);
    prepack_x<<<32 * HW, 256, 0, stream>>>(x, xp32);
    conv_main<<<dim3(NWG), 256, 0, stream>>>(Ap, Xp, out);
  } else {
    conv_fallback<<<dim3(2, NTOT / 128), 256, 0, stream>>>(x, w, out);
  }
}